// Round 7
// baseline (682.980 us; speedup 1.0000x reference)
//
#include <hip/hip_runtime.h>

#define NN 8192
#define SS 64
#define BSD 512                 // B*S
#define NS (NN*SS)              // 524288
#define NBS (NN*BSD)            // 4194304

typedef __attribute__((ext_vector_type(4))) _Float16 f16x4;
typedef __attribute__((ext_vector_type(8))) _Float16 f16x8;
typedef __attribute__((ext_vector_type(4))) float f32x4;

#define GLOAD_LDS16(gptr, lptr) \
    __builtin_amdgcn_global_load_lds((const __attribute__((address_space(1))) void*)(gptr), \
                                     (__attribute__((address_space(3))) void*)(lptr), 16, 0, 0)

// claimed (lane,elem)->k map inside a 32-k chunk; only needs to be identical
// for A and B packs (self-canceling bijection in the MFMA dot product).
// Empirically validated by round-3/5/6 passes with random asymmetric Mix.
__device__ __forceinline__ int kmap(int lane, int e) {
    return ((lane >> 4) << 2) + (e & 3) + ((e >> 2) << 4);
}

// ---------------------------------------------------------------- gate
__global__ void sigmoid_gate_kernel(const float* __restrict__ ent, float* __restrict__ gate) {
    int i = blockIdx.x * 256 + threadIdx.x;
    gate[i] = 1.0f / (1.0f + expf(-ent[i]));
}

// ================================================================= convA
// D[k][m] = Mix[k][m] - (k==m), split hi/lo f16.
// 64-row tiles: tile(mt64,kt) at (mt64*128+kt)*16384: hi 8KB [blk4][kk2][lane][16B], lo +8192.
__global__ __launch_bounds__(256) void convA_kernel(const float* __restrict__ Mx,
                                                    char* __restrict__ Ab) {
    __shared__ _Float16 Lh[64][136];
    __shared__ _Float16 Ll[64][136];
    const int t = threadIdx.x;
    const int kt = blockIdx.x, mt = blockIdx.y;   // mt: 128-col group (0..63)
    const int k0 = kt * 64, m0 = mt * 128;
    #pragma unroll
    for (int i = 0; i < 8; ++i) {
        int e = i * 256 + t;
        int kr = e >> 5, m4 = (e & 31) << 2;
        float4 v = *(const float4*)&Mx[(size_t)(k0 + kr) * NN + m0 + m4];
        int d = (k0 + kr) - (m0 + m4);     // subtract identity where k == m
        if (d == 0) v.x -= 1.0f;
        if (d == 1) v.y -= 1.0f;
        if (d == 2) v.z -= 1.0f;
        if (d == 3) v.w -= 1.0f;
        f16x4 h, l;
        h[0] = (_Float16)v.x; l[0] = (_Float16)(v.x - (float)h[0]);
        h[1] = (_Float16)v.y; l[1] = (_Float16)(v.y - (float)h[1]);
        h[2] = (_Float16)v.z; l[2] = (_Float16)(v.z - (float)h[2]);
        h[3] = (_Float16)v.w; l[3] = (_Float16)(v.w - (float)h[3]);
        *(f16x4*)&Lh[kr][m4] = h;
        *(f16x4*)&Ll[kr][m4] = l;
    }
    __syncthreads();
    #pragma unroll
    for (int j = 0; j < 4; ++j) {
        int idx  = j * 256 + t;            // 0..1023
        int h    = idx >> 9;               // which 64-row half
        int w    = idx & 511;              // [blk4][kk2][lane64]
        int blk  = w >> 7;
        int kk   = (w >> 6) & 1;
        int lane = w & 63;
        int col  = h * 64 + blk * 16 + (lane & 15);
        int kb   = kk * 32;
        f16x8 hv, lv;
        #pragma unroll
        for (int e = 0; e < 8; ++e) {
            int k = kb + kmap(lane, e);
            hv[e] = Lh[k][col];
            lv[e] = Ll[k][col];
        }
        char* tile = Ab + (((size_t)(mt * 2 + h) * 128 + kt) << 14);
        *(f16x8*)(tile + w * 16)        = hv;
        *(f16x8*)(tile + 8192 + w * 16) = lv;
    }
}

// ---------------------------------------------------------------- shared B pack
// Lh: [64 k][512 col] f16 of gated activation; Nh/Nl: [64 k][64 s] split of m_g.
// Bmain tile (16KB) per nbt; Bns tile (4KB = hi 2K | lo 2K) per nbt.
__device__ __forceinline__ void pack_B(const _Float16 (*Lh)[520],
                                       const _Float16 (*Nh)[72], const _Float16 (*Nl)[72],
                                       char* Bb, char* Nb, int kt, int t) {
    #pragma unroll
    for (int j = 0; j < 16; ++j) {
        int idx = j * 256 + t;             // 0..4095
        int nbt = idx >> 10, w = idx & 1023;
        int blk = w >> 7, kk = (w >> 6) & 1, lane = w & 63;
        int col = nbt * 128 + blk * 16 + (lane & 15);
        int kb = kk * 32;
        f16x8 hv;
        #pragma unroll
        for (int e = 0; e < 8; ++e)
            hv[e] = Lh[kb + kmap(lane, e)][col];
        *(f16x8*)(Bb + (((size_t)kt * 4 + nbt) << 14) + w * 16) = hv;
    }
    #pragma unroll
    for (int j = 0; j < 4; ++j) {
        int idx = j * 256 + t;             // 0..1023
        int nbt = idx >> 8, r = idx & 255;
        int part = r >> 7, kk = (r >> 6) & 1, lane = r & 63;
        int s = nbt * 16 + (lane & 15);
        int kb = kk * 32;
        f16x8 v;
        #pragma unroll
        for (int e = 0; e < 8; ++e) {
            int k = kb + kmap(lane, e);
            v[e] = part ? Nl[k][s] : Nh[k][s];
        }
        *(f16x8*)(Nb + (((size_t)kt * 4 + nbt) << 12) + part * 2048 + kk * 1024 + lane * 16) = v;
    }
}

// ================================================================= prep0 (layer 1 B)
__global__ __launch_bounds__(256) void prep0_kernel(const float* __restrict__ x,
                                                    const float* __restrict__ gate,
                                                    float* __restrict__ X,
                                                    char* __restrict__ Bb,
                                                    char* __restrict__ Nb,
                                                    float* __restrict__ mg32) {
    __shared__ _Float16 Lh[64][520];
    __shared__ _Float16 Nh[64][72];
    __shared__ _Float16 Nl[64][72];
    const int t = threadIdx.x;
    const int kt = blockIdx.x;
    const int n0 = kt * 64;
    #pragma unroll
    for (int i = 0; i < 4; ++i) {
        int e = i * 256 + t;           // 0..1023
        int kr = e >> 4;               // 0..63
        int s4 = (e & 15) << 2;        // 0..60
        float4 g = *(const float4*)&gate[(size_t)(n0 + kr) * 64 + s4];
        float4 ms = make_float4(0.f, 0.f, 0.f, 0.f);
        #pragma unroll
        for (int b = 0; b < 8; ++b) {
            float4 v = *(const float4*)&x[((size_t)b * NN + n0 + kr) * 64 + s4];
            ms.x += v.x; ms.y += v.y; ms.z += v.z; ms.w += v.w;
            v.x *= g.x; v.y *= g.y; v.z *= g.z; v.w *= g.w;
            *(float4*)&X[(size_t)(n0 + kr) * BSD + b * 64 + s4] = v;
            f16x4 h;
            h[0] = (_Float16)v.x; h[1] = (_Float16)v.y;
            h[2] = (_Float16)v.z; h[3] = (_Float16)v.w;
            *(f16x4*)&Lh[kr][b * 64 + s4] = h;
        }
        float4 mg4;
        mg4.x = ms.x * 0.125f * g.x; mg4.y = ms.y * 0.125f * g.y;
        mg4.z = ms.z * 0.125f * g.z; mg4.w = ms.w * 0.125f * g.w;
        *(float4*)&mg32[(size_t)(n0 + kr) * 64 + s4] = mg4;
        f16x4 mh, ml;
        mh[0] = (_Float16)mg4.x; ml[0] = (_Float16)(mg4.x - (float)mh[0]);
        mh[1] = (_Float16)mg4.y; ml[1] = (_Float16)(mg4.y - (float)mh[1]);
        mh[2] = (_Float16)mg4.z; ml[2] = (_Float16)(mg4.z - (float)mh[2]);
        mh[3] = (_Float16)mg4.w; ml[3] = (_Float16)(mg4.w - (float)mh[3]);
        *(f16x4*)&Nh[kr][s4] = mh;
        *(f16x4*)&Nl[kr][s4] = ml;
    }
    __syncthreads();
    pack_B(Lh, Nh, Nl, Bb, Nb, kt, t);
}

// ================================================================= gateconv (layers 2,3 B)
__global__ __launch_bounds__(256) void gateconv_kernel(float* __restrict__ X,
                                                       const float* __restrict__ gate,
                                                       const float* __restrict__ nsprev,
                                                       char* __restrict__ Bb,
                                                       char* __restrict__ Nb,
                                                       float* __restrict__ mg32) {
    __shared__ _Float16 Lh[64][520];
    __shared__ _Float16 Nh[64][72];
    __shared__ _Float16 Nl[64][72];
    const int t = threadIdx.x;
    const int kt = blockIdx.x;
    const int n0 = kt * 64;
    #pragma unroll
    for (int i = 0; i < 32; ++i) {
        int e = i * 256 + t;           // 0..8191
        int kr = e >> 7;               // 0..63
        int c4 = (e & 127) << 2;       // 0..508
        float4 v = *(const float4*)&X[(size_t)(n0 + kr) * BSD + c4];
        float4 g = *(const float4*)&gate[(size_t)(n0 + kr) * 64 + (c4 & 63)];
        v.x *= g.x; v.y *= g.y; v.z *= g.z; v.w *= g.w;
        *(float4*)&X[(size_t)(n0 + kr) * BSD + c4] = v;
        f16x4 h;
        h[0] = (_Float16)v.x; h[1] = (_Float16)v.y;
        h[2] = (_Float16)v.z; h[3] = (_Float16)v.w;
        *(f16x4*)&Lh[kr][c4] = h;
    }
    #pragma unroll
    for (int i = 0; i < 4; ++i) {
        int e = i * 256 + t;
        int kr = e >> 4;
        int s4 = (e & 15) << 2;
        float4 p = *(const float4*)&nsprev[(size_t)(n0 + kr) * 64 + s4];
        float4 g = *(const float4*)&gate[(size_t)(n0 + kr) * 64 + s4];
        float4 mg4;
        mg4.x = p.x * g.x; mg4.y = p.y * g.y; mg4.z = p.z * g.z; mg4.w = p.w * g.w;
        *(float4*)&mg32[(size_t)(n0 + kr) * 64 + s4] = mg4;
        f16x4 mh, ml;
        mh[0] = (_Float16)mg4.x; ml[0] = (_Float16)(mg4.x - (float)mh[0]);
        mh[1] = (_Float16)mg4.y; ml[1] = (_Float16)(mg4.y - (float)mh[1]);
        mh[2] = (_Float16)mg4.z; ml[2] = (_Float16)(mg4.z - (float)mh[2]);
        mh[3] = (_Float16)mg4.w; ml[3] = (_Float16)(mg4.w - (float)mh[3]);
        *(f16x4*)&Nh[kr][s4] = mh;
        *(f16x4*)&Nl[kr][s4] = ml;
    }
    __syncthreads();
    pack_B(Lh, Nh, Nl, Bb, Nb, kt, t);
}

// ================================================================= GEMM
// Main: X[m][c] = X_gated[m][c] + sum_k Dh[k][m]*Yg_f16[k][c]   (in-place X)
// ns:   ns[m][s] = mg[m][s] + sum_k (Dh*mh + Dh*ml + Dl*mh)[m][s]
// Block tile 64x(128 main + 16 ns), BK=64, 4 waves (wave = 64 rows x 32 cols).
// Grid 512 -> 2 blocks/CU (dbuf LDS 72KB). Single barrier per K-step:
// stage(next) -> compute(cur) -> vmcnt(0) -> s_barrier.
__global__ __launch_bounds__(256) void gemm_f16_kernel(const char* __restrict__ Ab,
                                                       const char* __restrict__ Bb,
                                                       const char* __restrict__ Nb,
                                                       float* X,
                                                       const float* __restrict__ mg,
                                                       float* __restrict__ nsout) {
    __shared__ char lds[2][36864];   // Ahi 8K | Alo 8K | Bm 16K | Bn 4K
    const int t = threadIdx.x;
    const int L = blockIdx.x;                    // 0..511
    // XCD swizzle: the 4 nbt-blocks of one mt share an XCD (A panel L2 reuse)
    const int mt  = (L & 7) + ((L >> 5) << 3);   // 0..127 (64-row tile idx)
    const int nbt = (L >> 3) & 3;                // 0..3
    const int lane = t & 63, wid = t >> 6;       // 4 waves; wave cols = wid*32

    auto stage = [&](int buf, int kt) {
        const char* ga = Ab + (((size_t)mt * 128 + kt) << 14);
        const char* gb = Bb + (((size_t)kt * 4 + nbt) << 14);
        const char* gn = Nb + (((size_t)kt * 4 + nbt) << 12);
        char* la = lds[buf];
        GLOAD_LDS16(ga + wid * 2048 + lane * 16,               la + wid * 2048);
        GLOAD_LDS16(ga + wid * 2048 + 1024 + lane * 16,        la + wid * 2048 + 1024);
        GLOAD_LDS16(ga + 8192 + wid * 2048 + lane * 16,        la + 8192 + wid * 2048);
        GLOAD_LDS16(ga + 8192 + wid * 2048 + 1024 + lane * 16, la + 8192 + wid * 2048 + 1024);
        #pragma unroll
        for (int i = 0; i < 4; ++i)
            GLOAD_LDS16(gb + wid * 4096 + i * 1024 + lane * 16,
                        la + 16384 + wid * 4096 + i * 1024);
        GLOAD_LDS16(gn + wid * 1024 + lane * 16,               la + 32768 + wid * 1024);
    };   // 9 loads per wave, uniform

    f32x4 accm[4][2];
    #pragma unroll
    for (int fi = 0; fi < 4; ++fi) {
        accm[fi][0] = (f32x4){0.f, 0.f, 0.f, 0.f};
        accm[fi][1] = (f32x4){0.f, 0.f, 0.f, 0.f};
    }
    f32x4 accn = (f32x4){0.f, 0.f, 0.f, 0.f};

    stage(0, 0);
    asm volatile("s_waitcnt vmcnt(0)" ::: "memory");
    __builtin_amdgcn_s_barrier();
    for (int kt = 0; kt < 128; ++kt) {
        const int cur = kt & 1;
        if (kt < 127) stage(cur ^ 1, kt + 1);                 // prefetch next tile
        const char* base = lds[cur];
        const char* A_ = base + lane * 16;                    // +fi*2048+kk*1024 (+8192 lo)
        const char* Bm = base + 16384 + wid * 4096 + lane * 16;
        const char* Bn = base + 32768 + lane * 16;
        #pragma unroll
        for (int kk = 0; kk < 2; ++kk) {
            const int ko = kk * 1024;
            f16x8 bm0 = *(const f16x8*)(Bm + ko);
            f16x8 bm1 = *(const f16x8*)(Bm + 2048 + ko);
            f16x8 bnh = *(const f16x8*)(Bn + ko);
            f16x8 bnl = *(const f16x8*)(Bn + 2048 + ko);
            f16x8 ahn = *(const f16x8*)(A_ + wid * 2048 + ko);
            f16x8 aln = *(const f16x8*)(A_ + 8192 + wid * 2048 + ko);
            #pragma unroll
            for (int fi = 0; fi < 4; ++fi) {
                f16x8 ah = *(const f16x8*)(A_ + fi * 2048 + ko);
                accm[fi][0] = __builtin_amdgcn_mfma_f32_16x16x32_f16(ah, bm0, accm[fi][0], 0, 0, 0);
                accm[fi][1] = __builtin_amdgcn_mfma_f32_16x16x32_f16(ah, bm1, accm[fi][1], 0, 0, 0);
            }
            accn = __builtin_amdgcn_mfma_f32_16x16x32_f16(ahn, bnh, accn, 0, 0, 0);
            accn = __builtin_amdgcn_mfma_f32_16x16x32_f16(ahn, bnl, accn, 0, 0, 0);
            accn = __builtin_amdgcn_mfma_f32_16x16x32_f16(aln, bnh, accn, 0, 0, 0);
        }
        asm volatile("s_waitcnt vmcnt(0)" ::: "memory");      // own prefetch landed
        __builtin_amdgcn_s_barrier();                         // tile ready + reads done
    }

    // D layout (m89-verified): col = lane&15, row = (lane>>4)*4 + reg
    const int row0 = mt * 64 + ((lane >> 4) << 2);
    const int col0 = nbt * 128 + wid * 32 + (lane & 15);
    #pragma unroll
    for (int fi = 0; fi < 4; ++fi)
        #pragma unroll
        for (int fj = 0; fj < 2; ++fj)
            #pragma unroll
            for (int j = 0; j < 4; ++j) {
                size_t idx = (size_t)(row0 + fi * 16 + j) * BSD + col0 + fj * 16;
                X[idx] = accm[fi][fj][j] + X[idx];   // identity term (gated input, fp32)
            }
    const int nr0 = mt * 64 + wid * 16 + ((lane >> 4) << 2);
    const int nc  = nbt * 16 + (lane & 15);
    #pragma unroll
    for (int j = 0; j < 4; ++j) {
        size_t nidx = (size_t)(nr0 + j) * 64 + nc;
        nsout[nidx] = accn[j] + mg[nidx];            // identity term (gated mean, fp32)
    }
}

// ================================================================= readout
__global__ __launch_bounds__(256) void readout_kernel(const float* __restrict__ X3,
                                                      const float* __restrict__ W,
                                                      float* __restrict__ out) {
    __shared__ float Wt[64][65];
    __shared__ float xr[512];
    const int n = blockIdx.x;
    const int t = threadIdx.x;
    for (int e = t; e < 4096; e += 256) {
        int s = e >> 6, sp = e & 63;
        Wt[sp][s] = W[e];
    }
    xr[t]       = X3[(size_t)n * BSD + t];
    xr[t + 256] = X3[(size_t)n * BSD + 256 + t];
    __syncthreads();
    const int b1 = t >> 6;
    const int s  = t & 63;
    float acc0 = 0.0f, acc1 = 0.0f;
    #pragma unroll
    for (int sp = 0; sp < 64; ++sp) {
        float w = Wt[sp][s];
        acc0 += w * xr[b1 * 64 + sp];
        acc1 += w * xr[(b1 + 4) * 64 + sp];
    }
    out[((size_t)b1 * NN + n) * SS + s]       = acc0;
    out[((size_t)(b1 + 4) * NN + n) * SS + s] = acc1;
}

// ================================== temporal avg + enc + dec + top-k collapse
__global__ void nsfinal_kernel(const float* __restrict__ ns0,
                               const float* __restrict__ enc_w, const float* __restrict__ enc_b,
                               const float* __restrict__ dec_w, const float* __restrict__ dec_b,
                               float* __restrict__ out_ns) {
    int gtid = blockIdx.x * 256 + threadIdx.x;
    int lane = gtid & 63;
    const float r = 0.9f;
    const float wsum = 1.0f + r + r * r;
    float tns = (ns0[gtid] * (r * r) + ns0[NS + gtid] * r + ns0[2 * NS + gtid]) / wsum;
    float v = dec_b[lane];
    #pragma unroll
    for (int c = 0; c < 16; ++c) {
        float p = tns * enc_w[c * 64 + lane];
        #pragma unroll
        for (int off = 32; off; off >>= 1) p += __shfl_xor(p, off, 64);
        float h = fmaxf(p + enc_b[c], 0.0f);
        v += h * dec_w[lane * 16 + c];
    }
    float av = fabsf(v);
    int cnt = 0;
    for (int j = 0; j < 64; ++j) {
        float o = __shfl(av, j, 64);
        cnt += (o > av) ? 1 : 0;
    }
    out_ns[gtid] = (cnt < 8) ? v : 0.0f;
}

// ================================================================= launch
extern "C" void kernel_launch(void* const* d_in, const int* in_sizes, int n_in,
                              void* d_out, int out_size, void* d_ws, size_t ws_size,
                              hipStream_t stream) {
    const float* x      = (const float*)d_in[0];
    const float* ent    = (const float*)d_in[1];
    const float* mixing = (const float*)d_in[2];
    const float* r_w    = (const float*)d_in[3];
    const float* enc_w  = (const float*)d_in[4];
    const float* enc_b  = (const float*)d_in[5];
    const float* dec_w  = (const float*)d_in[6];
    const float* dec_b  = (const float*)d_in[7];
    float* out = (float*)d_out;

    char*  Ab   = (char*)d_ws;                    // 256 MB  (D hi|lo 64-row tiles)
    char*  Bb   = Ab + 268435456ull;              // 8 MB    (B main f16 tiles)
    char*  Nb   = Bb + 8388608ull;                // 2 MB    (B ns split tiles)
    float* X    = (float*)(Nb + 2097152ull);      // 16 MB   (activation, in-place)
    float* mg32 = X + NBS;                        // 2 MB    (gated mean fp32)
    float* ns0  = mg32 + NS;                      // 6 MB    (3 layer means)
    float* gate = ns0 + 3 * (size_t)NS;           // 2 MB

    sigmoid_gate_kernel<<<NS / 256, 256, 0, stream>>>(ent, gate);
    convA_kernel<<<dim3(128, 64), 256, 0, stream>>>(mixing, Ab);
    prep0_kernel<<<128, 256, 0, stream>>>(x, gate, X, Bb, Nb, mg32);

    for (int l = 0; l < 3; ++l) {
        gemm_f16_kernel<<<512, 256, 0, stream>>>(Ab, Bb, Nb, X, mg32, ns0 + (size_t)l * NS);
        if (l < 2)
            gateconv_kernel<<<128, 256, 0, stream>>>(X, gate, ns0 + (size_t)l * NS, Bb, Nb, mg32);
    }

    readout_kernel<<<NN, 256, 0, stream>>>(X, r_w, out);
    nsfinal_kernel<<<2048, 256, 0, stream>>>(ns0, enc_w, enc_b, dec_w, dec_b, out + NBS);
}